// Round 1
// baseline (890.971 us; speedup 1.0000x reference)
//
#include <hip/hip_runtime.h>

#define NN 100000
#define NE 1600000
#define DIM 64
#define NL 3
#define SLOPE 0.2f

static __device__ __forceinline__ float lrelu(float x) { return x > 0.f ? x : SLOPE * x; }

// ---------------- CSR build ----------------

__global__ __launch_bounds__(256) void k_hist(const int* __restrict__ ei, int* __restrict__ deg) {
    int e = blockIdx.x * 256 + threadIdx.x;
    if (e < NE) atomicAdd(&deg[ei[NE + e]], 1);
}

// block scans 1024 elements (256 threads x 4)
__global__ __launch_bounds__(256) void k_scan1(const int* __restrict__ deg, int* __restrict__ part,
                                               int* __restrict__ bsum) {
    __shared__ int sm[256];
    int t = threadIdx.x;
    int base = blockIdx.x * 1024 + t * 4;
    int v[4];
    int run = 0;
#pragma unroll
    for (int j = 0; j < 4; j++) {
        int idx = base + j;
        int d = (idx < NN) ? deg[idx] : 0;
        v[j] = run;
        run += d;
    }
    sm[t] = run;
    __syncthreads();
    for (int off = 1; off < 256; off <<= 1) {
        int x = (t >= off) ? sm[t - off] : 0;
        __syncthreads();
        sm[t] += x;
        __syncthreads();
    }
    int ex = (t == 0) ? 0 : sm[t - 1];
    if (t == 255) bsum[blockIdx.x] = sm[255];
#pragma unroll
    for (int j = 0; j < 4; j++) {
        int idx = base + j;
        if (idx < NN) part[idx] = ex + v[j];
    }
}

__global__ void k_scan2(int* bsum, int nb) {
    __shared__ int sm[256];
    int t = threadIdx.x;
    sm[t] = (t < nb) ? bsum[t] : 0;
    __syncthreads();
    for (int off = 1; off < 256; off <<= 1) {
        int x = (t >= off) ? sm[t - off] : 0;
        __syncthreads();
        sm[t] += x;
        __syncthreads();
    }
    if (t < nb) bsum[t] = (t == 0) ? 0 : sm[t - 1];
}

__global__ __launch_bounds__(256) void k_scan3(const int* __restrict__ part, const int* __restrict__ bsum,
                                               int* __restrict__ offs, int* __restrict__ cur) {
    int i = blockIdx.x * 256 + threadIdx.x;
    if (i < NN) {
        int o = part[i] + bsum[i >> 10];
        offs[i] = o;
        cur[i] = o;
    }
    if (i == NN) offs[NN] = NE;
}

__global__ __launch_bounds__(256) void k_scatter(const int* __restrict__ ei, int* __restrict__ cur,
                                                 int* __restrict__ csr) {
    int e = blockIdx.x * 256 + threadIdx.x;
    if (e < NE) {
        int dst = ei[NE + e];
        int src = ei[e];
        int pos = atomicAdd(&cur[dst], 1);
        csr[pos] = src;
    }
}

// ---------------- per-layer passes ----------------

// wave per node: hw = h @ W, alpha_s = hw . a_src, alpha_d = hw . a_dst
__global__ __launch_bounds__(256) void k_transform(const float* __restrict__ h, const float* __restrict__ W,
                                                   const float* __restrict__ avs, const float* __restrict__ avd,
                                                   float* __restrict__ hw, float* __restrict__ als,
                                                   float* __restrict__ ald) {
    int t = threadIdx.x, wave = t >> 6, lane = t & 63;
    float wreg[64];  // W[:, lane] held in registers
#pragma unroll
    for (int k = 0; k < 64; k++) wreg[k] = W[k * 64 + lane];
    float asl = avs[lane], adl = avd[lane];
    int nw = gridDim.x * 4;
    for (int i = blockIdx.x * 4 + wave; i < NN; i += nw) {
        float v = h[(size_t)i * 64 + lane];
        float a0 = 0.f, a1 = 0.f;
#pragma unroll
        for (int k = 0; k < 64; k += 2) {
            float h0 = __int_as_float(__builtin_amdgcn_readlane(__float_as_int(v), k));
            float h1 = __int_as_float(__builtin_amdgcn_readlane(__float_as_int(v), k + 1));
            a0 = fmaf(h0, wreg[k], a0);
            a1 = fmaf(h1, wreg[k + 1], a1);
        }
        float hv = a0 + a1;
        hw[(size_t)i * 64 + lane] = hv;
        float ps = hv * asl, pd = hv * adl;
#pragma unroll
        for (int off = 32; off; off >>= 1) {
            ps += __shfl_xor(ps, off);
            pd += __shfl_xor(pd, off);
        }
        if (lane == 0) {
            als[i] = ps;
            ald[i] = pd;
        }
    }
}

// wave per dst node, lane = dim; online softmax over incoming edges + self loop
__global__ __launch_bounds__(256) void k_aggregate(const float* __restrict__ hw, const float* __restrict__ als,
                                                   const float* __restrict__ ald, const int* __restrict__ offs,
                                                   const int* __restrict__ csr, const float* __restrict__ bv,
                                                   float* __restrict__ out) {
    int t = threadIdx.x, wave = t >> 6, lane = t & 63;
    int i = blockIdx.x * 4 + wave;
    if (i >= NN) return;
    float ad = ald[i];
    // self loop initializes the running softmax state
    float m = lrelu(als[i] + ad);
    float s = 1.f;
    float acc = hw[(size_t)i * 64 + lane];
    int beg = offs[i], end = offs[i + 1];
    for (int j = beg; j < end; ++j) {
        int src = csr[j];
        float e = lrelu(als[src] + ad);  // wave-uniform
        float hv = hw[(size_t)src * 64 + lane];
        if (e <= m) {  // uniform branch: common case, no rescale
            float p = __expf(e - m);
            s += p;
            acc = fmaf(p, hv, acc);
        } else {  // new max: rescale old state
            float sc = __expf(m - e);
            s = fmaf(s, sc, 1.f);
            acc = fmaf(acc, sc, hv);
            m = e;
        }
    }
    float o = acc / s + bv[lane];
    o = fminf(fmaxf(o, -1.f), 1.f);
    out[(size_t)i * 64 + lane] = o;
}

// ---------------- launch ----------------

extern "C" void kernel_launch(void* const* d_in, const int* in_sizes, int n_in, void* d_out, int out_size,
                              void* d_ws, size_t ws_size, hipStream_t stream) {
    const float* x = (const float*)d_in[0];
    const int* ei = (const int*)d_in[1];  // [2, NE] int32
    const float* W = (const float*)d_in[2];
    const float* a_s = (const float*)d_in[3];
    const float* a_d = (const float*)d_in[4];
    const float* b = (const float*)d_in[5];
    float* out = (float*)d_out;

    char* w = (char*)d_ws;
    auto alloc = [&](size_t bytes) -> char* {
        char* p = w;
        w += (bytes + 255) & ~(size_t)255;
        return p;
    };
    int* deg = (int*)alloc(NN * 4);
    int* part = (int*)alloc(NN * 4);
    int* offs = (int*)alloc((NN + 1) * 4);
    int* cur = (int*)alloc(NN * 4);
    int* bsum = (int*)alloc(1024);
    int* csr = (int*)alloc((size_t)NE * 4);
    float* als = (float*)alloc(NN * 4);
    float* ald = (float*)alloc(NN * 4);
    float* hwb = (float*)alloc((size_t)NN * DIM * 4);  // hw buffer

    // CSR by dst (same inputs every call -> same work every call)
    hipMemsetAsync(deg, 0, NN * 4, stream);
    k_hist<<<(NE + 255) / 256, 256, 0, stream>>>(ei, deg);
    int nb = (NN + 1023) / 1024;
    k_scan1<<<nb, 256, 0, stream>>>(deg, part, bsum);
    k_scan2<<<1, 256, 0, stream>>>(bsum, nb);
    k_scan3<<<(NN + 1 + 255) / 256, 256, 0, stream>>>(part, bsum, offs, cur);
    k_scatter<<<(NE + 255) / 256, 256, 0, stream>>>(ei, cur, csr);

    // 3 GAT layers; d_out doubles as the h ping buffer (h dead once hw computed)
    const float* hin = x;
    for (int l = 0; l < NL; l++) {
        k_transform<<<1600, 256, 0, stream>>>(hin, W + l * DIM * DIM, a_s + l * DIM, a_d + l * DIM, hwb, als, ald);
        k_aggregate<<<(NN + 3) / 4, 256, 0, stream>>>(hwb, als, ald, offs, csr, b + l * DIM, out);
        hin = out;
    }
}

// Round 3
// 594.786 us; speedup vs baseline: 1.4980x; 1.4980x over previous
//
#include <hip/hip_runtime.h>

#define NN 100000
#define NE 1600000
#define DIM 64
#define NL 3
#define SLOPE 0.2f

static __device__ __forceinline__ float lrelu(float x) { return x > 0.f ? x : SLOPE * x; }
static __device__ __forceinline__ float rdlane_f(float v, int l) {
    return __int_as_float(__builtin_amdgcn_readlane(__float_as_int(v), l));
}

// ---------------- CSR build ----------------

__global__ __launch_bounds__(256) void k_hist(const int* __restrict__ ei, int* __restrict__ deg) {
    int e = blockIdx.x * 256 + threadIdx.x;
    if (e < NE) atomicAdd(&deg[ei[NE + e]], 1);
}

// block scans 1024 elements (256 threads x 4)
__global__ __launch_bounds__(256) void k_scan1(const int* __restrict__ deg, int* __restrict__ part,
                                               int* __restrict__ bsum) {
    __shared__ int sm[256];
    int t = threadIdx.x;
    int base = blockIdx.x * 1024 + t * 4;
    int v[4];
    int run = 0;
#pragma unroll
    for (int j = 0; j < 4; j++) {
        int idx = base + j;
        int d = (idx < NN) ? deg[idx] : 0;
        v[j] = run;
        run += d;
    }
    sm[t] = run;
    __syncthreads();
    for (int off = 1; off < 256; off <<= 1) {
        int x = (t >= off) ? sm[t - off] : 0;
        __syncthreads();
        sm[t] += x;
        __syncthreads();
    }
    int ex = (t == 0) ? 0 : sm[t - 1];
    if (t == 255) bsum[blockIdx.x] = sm[255];
#pragma unroll
    for (int j = 0; j < 4; j++) {
        int idx = base + j;
        if (idx < NN) part[idx] = ex + v[j];
    }
}

__global__ void k_scan2(int* bsum, int nb) {
    __shared__ int sm[256];
    int t = threadIdx.x;
    sm[t] = (t < nb) ? bsum[t] : 0;
    __syncthreads();
    for (int off = 1; off < 256; off <<= 1) {
        int x = (t >= off) ? sm[t - off] : 0;
        __syncthreads();
        sm[t] += x;
        __syncthreads();
    }
    if (t < nb) bsum[t] = (t == 0) ? 0 : sm[t - 1];
}

__global__ __launch_bounds__(256) void k_scan3(const int* __restrict__ part, const int* __restrict__ bsum,
                                               int* __restrict__ offs, int* __restrict__ cur) {
    int i = blockIdx.x * 256 + threadIdx.x;
    if (i < NN) {
        int o = part[i] + bsum[i >> 10];
        offs[i] = o;
        cur[i] = o;
    }
    if (i == NN) offs[NN] = NE;
}

__global__ __launch_bounds__(256) void k_scatter(const int* __restrict__ ei, int* __restrict__ cur,
                                                 int* __restrict__ csr) {
    int e = blockIdx.x * 256 + threadIdx.x;
    if (e < NE) {
        int dst = ei[NE + e];
        int src = ei[e];
        int pos = atomicAdd(&cur[dst], 1);
        csr[pos] = src;
    }
}

// ---------------- per-layer passes ----------------

// wave per node: hw = h @ W, alpha_s = hw . a_src, alpha_d = hw . a_dst
__global__ __launch_bounds__(256) void k_transform(const float* __restrict__ h, const float* __restrict__ W,
                                                   const float* __restrict__ avs, const float* __restrict__ avd,
                                                   float* __restrict__ hw, float* __restrict__ als,
                                                   float* __restrict__ ald) {
    int t = threadIdx.x, wave = t >> 6, lane = t & 63;
    float wreg[64];  // W[:, lane] held in registers
#pragma unroll
    for (int k = 0; k < 64; k++) wreg[k] = W[k * 64 + lane];
    float asl = avs[lane], adl = avd[lane];
    int nw = gridDim.x * 4;
    for (int i = blockIdx.x * 4 + wave; i < NN; i += nw) {
        float v = h[(size_t)i * 64 + lane];
        float a0 = 0.f, a1 = 0.f;
#pragma unroll
        for (int k = 0; k < 64; k += 2) {
            float h0 = rdlane_f(v, k);
            float h1 = rdlane_f(v, k + 1);
            a0 = fmaf(h0, wreg[k], a0);
            a1 = fmaf(h1, wreg[k + 1], a1);
        }
        float hv = a0 + a1;
        hw[(size_t)i * 64 + lane] = hv;
        float ps = hv * asl, pd = hv * adl;
#pragma unroll
        for (int off = 32; off; off >>= 1) {
            ps += __shfl_xor(ps, off);
            pd += __shfl_xor(pd, off);
        }
        if (lane == 0) {
            als[i] = ps;
            ald[i] = pd;
        }
    }
}

// wave per dst node. Phase 1: lanes = incoming edges (coalesced csr load, als gather,
// shfl reductions for segment-softmax max & sum). Phase 2: lanes = dims; readlane-broadcast
// (src_j, p_j) and issue 4 independent SGPR-base row loads per batch. Padding lanes have
// p=0, so over-read rows contribute nothing (no tail branch).
__global__ __launch_bounds__(256) void k_aggregate(const float* __restrict__ hw, const float* __restrict__ als,
                                                   const float* __restrict__ ald, const int* __restrict__ offs,
                                                   const int* __restrict__ csr, const float* __restrict__ bv,
                                                   float* __restrict__ out) {
    int t = threadIdx.x, wave = t >> 6, lane = t & 63;
    int i = blockIdx.x * 4 + wave;
    if (i >= NN) return;
    float ad = ald[i];
    // self loop initializes running softmax state (weight exp(eself-m)=1)
    float m = lrelu(als[i] + ad);
    float s = 1.f;
    float acc = hw[(size_t)i * 64 + lane];
    int beg = offs[i], end = offs[i + 1];
    for (int cb = beg; cb < end; cb += 64) {
        int cnt = end - cb;
        if (cnt > 64) cnt = 64;
        // phase 1: per-edge logits, lane = edge
        int src = 0;
        float e = -1e30f;
        if (lane < cnt) {
            src = csr[cb + lane];
            e = lrelu(als[src] + ad);
        }
        float cm = e;
#pragma unroll
        for (int off = 32; off; off >>= 1) cm = fmaxf(cm, __shfl_xor(cm, off));
        float mn = fmaxf(m, cm);
        float p = (lane < cnt) ? __expf(e - mn) : 0.f;
        float cs = p;
#pragma unroll
        for (int off = 32; off; off >>= 1) cs += __shfl_xor(cs, off);
        float sc = __expf(m - mn);  // <= 1
        s = fmaf(s, sc, cs);
        acc *= sc;
        m = mn;
        // phase 2: weighted gather, lane = dim; batches of 4 independent loads
        int cnt4 = (cnt + 3) & ~3;
        for (int j = 0; j < cnt4; j += 4) {
            int s0 = __builtin_amdgcn_readlane(src, j);
            int s1 = __builtin_amdgcn_readlane(src, j + 1);
            int s2 = __builtin_amdgcn_readlane(src, j + 2);
            int s3 = __builtin_amdgcn_readlane(src, j + 3);
            float p0 = rdlane_f(p, j);
            float p1 = rdlane_f(p, j + 1);
            float p2 = rdlane_f(p, j + 2);
            float p3 = rdlane_f(p, j + 3);
            float h0 = hw[(size_t)s0 * 64 + lane];
            float h1 = hw[(size_t)s1 * 64 + lane];
            float h2 = hw[(size_t)s2 * 64 + lane];
            float h3 = hw[(size_t)s3 * 64 + lane];
            acc = fmaf(p0, h0, acc);
            acc = fmaf(p1, h1, acc);
            acc = fmaf(p2, h2, acc);
            acc = fmaf(p3, h3, acc);
        }
    }
    float o = acc / s + bv[lane];
    o = fminf(fmaxf(o, -1.f), 1.f);
    out[(size_t)i * 64 + lane] = o;
}

// ---------------- launch ----------------

extern "C" void kernel_launch(void* const* d_in, const int* in_sizes, int n_in, void* d_out, int out_size,
                              void* d_ws, size_t ws_size, hipStream_t stream) {
    const float* x = (const float*)d_in[0];
    const int* ei = (const int*)d_in[1];  // [2, NE] int32
    const float* W = (const float*)d_in[2];
    const float* a_s = (const float*)d_in[3];
    const float* a_d = (const float*)d_in[4];
    const float* b = (const float*)d_in[5];
    float* out = (float*)d_out;

    char* w = (char*)d_ws;
    auto alloc = [&](size_t bytes) -> char* {
        char* p = w;
        w += (bytes + 255) & ~(size_t)255;
        return p;
    };
    int* deg = (int*)alloc(NN * 4);
    int* part = (int*)alloc(NN * 4);
    int* offs = (int*)alloc((NN + 1) * 4);
    int* cur = (int*)alloc(NN * 4);
    int* bsum = (int*)alloc(1024);
    int* csr = (int*)alloc((size_t)NE * 4);
    float* als = (float*)alloc(NN * 4);
    float* ald = (float*)alloc(NN * 4);
    float* hwb = (float*)alloc((size_t)NN * DIM * 4);  // hw buffer

    // CSR by dst (same inputs every call -> same work every call)
    hipMemsetAsync(deg, 0, NN * 4, stream);
    k_hist<<<(NE + 255) / 256, 256, 0, stream>>>(ei, deg);
    int nb = (NN + 1023) / 1024;
    k_scan1<<<nb, 256, 0, stream>>>(deg, part, bsum);
    k_scan2<<<1, 256, 0, stream>>>(bsum, nb);
    k_scan3<<<(NN + 1 + 255) / 256, 256, 0, stream>>>(part, bsum, offs, cur);
    k_scatter<<<(NE + 255) / 256, 256, 0, stream>>>(ei, cur, csr);

    // 3 GAT layers; d_out doubles as the h ping buffer (h dead once hw computed)
    const float* hin = x;
    for (int l = 0; l < NL; l++) {
        k_transform<<<1600, 256, 0, stream>>>(hin, W + l * DIM * DIM, a_s + l * DIM, a_d + l * DIM, hwb, als, ald);
        k_aggregate<<<(NN + 3) / 4, 256, 0, stream>>>(hwb, als, ald, offs, csr, b + l * DIM, out);
        hin = out;
    }
}

// Round 4
// 456.348 us; speedup vs baseline: 1.9524x; 1.3034x over previous
//
#include <hip/hip_runtime.h>

#define NN 100000
#define NE 1600000
#define DIM 64
#define NL 3
#define SLOPE 0.2f

#define BSH 9                      // 512 nodes per bucket
#define NBUCK ((NN + 511) >> BSH)  // 196
#define EPT 16
#define TILE (256 * EPT)  // 4096 edges per partition tile

static __device__ __forceinline__ float lrelu(float x) { return x > 0.f ? x : SLOPE * x; }
static __device__ __forceinline__ float rdlane_f(float v, int l) {
    return __int_as_float(__builtin_amdgcn_readlane(__float_as_int(v), l));
}

// ---------------- CSR build: LDS-binned two-level counting sort ----------------

// per-block LDS histogram over dst buckets, one global atomic per block x bucket
__global__ __launch_bounds__(256) void k_bucket_hist(const int* __restrict__ ei, int* __restrict__ bcnt) {
    __shared__ int h[256];
    int t = threadIdx.x;
    h[t] = 0;
    __syncthreads();
    for (int e = blockIdx.x * 256 + t; e < NE; e += 256 * 256) atomicAdd(&h[ei[NE + e] >> BSH], 1);
    __syncthreads();
    if (t < NBUCK && h[t]) atomicAdd(&bcnt[t], h[t]);
}

__global__ void k_bucket_scan(const int* __restrict__ bcnt, int* __restrict__ bbase, int* __restrict__ bcur,
                              int* __restrict__ offs) {
    __shared__ int sm[256];
    int t = threadIdx.x;
    sm[t] = (t < NBUCK) ? bcnt[t] : 0;
    __syncthreads();
    for (int off = 1; off < 256; off <<= 1) {
        int x = (t >= off) ? sm[t - off] : 0;
        __syncthreads();
        sm[t] += x;
        __syncthreads();
    }
    if (t < NBUCK) {
        int ex = (t == 0) ? 0 : sm[t - 1];
        bbase[t] = ex;
        bcur[t] = ex;
    }
    if (t == 0) {
        bbase[NBUCK] = NE;
        offs[NN] = NE;
    }
}

// rank tile edges per bucket in LDS, reorder tile so same-bucket edges are contiguous,
// claim global space (1 atomic per bucket per tile), copy out coalesced.
__global__ __launch_bounds__(256) void k_partition(const int* __restrict__ ei, int* __restrict__ bcur,
                                                   int2* __restrict__ pairs) {
    __shared__ int2 tile[TILE];
    __shared__ int cnt[256], ofsx[256], gdel[256], sm[256];
    int t = threadIdx.x;
    int ts = blockIdx.x * TILE;
    int tilecnt = NE - ts;
    if (tilecnt > TILE) tilecnt = TILE;
    cnt[t] = 0;
    __syncthreads();
    int srcv[EPT], dstv[EPT], rk[EPT];
#pragma unroll
    for (int k = 0; k < EPT; k++) {
        int e = ts + k * 256 + t;
        if (e < NE) {
            srcv[k] = ei[e];
            dstv[k] = ei[NE + e];
            rk[k] = atomicAdd(&cnt[dstv[k] >> BSH], 1);
        } else {
            rk[k] = -1;
        }
    }
    __syncthreads();
    sm[t] = cnt[t];
    __syncthreads();
    for (int off = 1; off < 256; off <<= 1) {
        int x = (t >= off) ? sm[t - off] : 0;
        __syncthreads();
        sm[t] += x;
        __syncthreads();
    }
    ofsx[t] = (t == 0) ? 0 : sm[t - 1];
    __syncthreads();
#pragma unroll
    for (int k = 0; k < EPT; k++) {
        if (rk[k] >= 0) tile[ofsx[dstv[k] >> BSH] + rk[k]] = make_int2(srcv[k], dstv[k]);
    }
    if (t < NBUCK && cnt[t]) gdel[t] = atomicAdd(&bcur[t], cnt[t]) - ofsx[t];
    __syncthreads();
    for (int i = t; i < tilecnt; i += 256) {
        int2 p = tile[i];
        pairs[gdel[p.y >> BSH] + i] = p;
    }
}

// one block per bucket: per-node counts + scan in LDS, then scatter src into the
// bucket's contiguous csr segment (L2-resident). Emits global offs coalesced.
__global__ __launch_bounds__(256) void k_node_csr(const int2* __restrict__ pairs, const int* __restrict__ bbase,
                                                  int* __restrict__ offs, int* __restrict__ csr) {
    __shared__ int deg[512], sofs[512], scur[512], sm[256];
    int t = threadIdx.x;
    int b = blockIdx.x;
    int nodeBase = b << BSH;
    int nNodes = NN - nodeBase;
    if (nNodes > 512) nNodes = 512;
    deg[t] = 0;
    deg[t + 256] = 0;
    __syncthreads();
    int ebeg = bbase[b], eend = bbase[b + 1];
    for (int i = ebeg + t; i < eend; i += 256) atomicAdd(&deg[pairs[i].y - nodeBase], 1);
    __syncthreads();
    int a0 = deg[2 * t], a1 = deg[2 * t + 1];
    sm[t] = a0 + a1;
    __syncthreads();
    for (int off = 1; off < 256; off <<= 1) {
        int x = (t >= off) ? sm[t - off] : 0;
        __syncthreads();
        sm[t] += x;
        __syncthreads();
    }
    int base = (t == 0) ? 0 : sm[t - 1];
    sofs[2 * t] = base;
    sofs[2 * t + 1] = base + a0;
    scur[2 * t] = 0;
    scur[2 * t + 1] = 0;
    __syncthreads();
    for (int n = t; n < nNodes; n += 256) offs[nodeBase + n] = ebeg + sofs[n];
    for (int i = ebeg + t; i < eend; i += 256) {
        int2 p = pairs[i];
        int ln = p.y - nodeBase;
        int r = atomicAdd(&scur[ln], 1);
        csr[ebeg + sofs[ln] + r] = p.x;
    }
}

// ---------------- per-layer passes ----------------

// wave per node: hw = h @ W, alpha_s = hw . a_src, alpha_d = hw . a_dst
__global__ __launch_bounds__(256) void k_transform(const float* __restrict__ h, const float* __restrict__ W,
                                                   const float* __restrict__ avs, const float* __restrict__ avd,
                                                   float* __restrict__ hw, float* __restrict__ als,
                                                   float* __restrict__ ald) {
    int t = threadIdx.x, wave = t >> 6, lane = t & 63;
    float wreg[64];  // W[:, lane] held in registers
#pragma unroll
    for (int k = 0; k < 64; k++) wreg[k] = W[k * 64 + lane];
    float asl = avs[lane], adl = avd[lane];
    int nw = gridDim.x * 4;
    for (int i = blockIdx.x * 4 + wave; i < NN; i += nw) {
        float v = h[(size_t)i * 64 + lane];
        float a0 = 0.f, a1 = 0.f;
#pragma unroll
        for (int k = 0; k < 64; k += 2) {
            float h0 = rdlane_f(v, k);
            float h1 = rdlane_f(v, k + 1);
            a0 = fmaf(h0, wreg[k], a0);
            a1 = fmaf(h1, wreg[k + 1], a1);
        }
        float hv = a0 + a1;
        hw[(size_t)i * 64 + lane] = hv;
        float ps = hv * asl, pd = hv * adl;
#pragma unroll
        for (int off = 32; off; off >>= 1) {
            ps += __shfl_xor(ps, off);
            pd += __shfl_xor(pd, off);
        }
        if (lane == 0) {
            als[i] = ps;
            ald[i] = pd;
        }
    }
}

// wave per dst node. Phase 1: lanes = incoming edges (coalesced csr load, als gather,
// shfl reductions for segment-softmax max & sum). Phase 2: lanes = dims; readlane-broadcast
// (src_j, p_j), 4 independent row loads per batch; padding lanes carry p=0.
__global__ __launch_bounds__(256) void k_aggregate(const float* __restrict__ hw, const float* __restrict__ als,
                                                   const float* __restrict__ ald, const int* __restrict__ offs,
                                                   const int* __restrict__ csr, const float* __restrict__ bv,
                                                   float* __restrict__ out) {
    int t = threadIdx.x, wave = t >> 6, lane = t & 63;
    int i = blockIdx.x * 4 + wave;
    if (i >= NN) return;
    float ad = ald[i];
    // self loop initializes running softmax state (weight exp(eself-m)=1)
    float m = lrelu(als[i] + ad);
    float s = 1.f;
    float acc = hw[(size_t)i * 64 + lane];
    int beg = offs[i], end = offs[i + 1];
    for (int cb = beg; cb < end; cb += 64) {
        int cnt = end - cb;
        if (cnt > 64) cnt = 64;
        // phase 1: per-edge logits, lane = edge
        int src = 0;
        float e = -1e30f;
        if (lane < cnt) {
            src = csr[cb + lane];
            e = lrelu(als[src] + ad);
        }
        float cm = e;
#pragma unroll
        for (int off = 32; off; off >>= 1) cm = fmaxf(cm, __shfl_xor(cm, off));
        float mn = fmaxf(m, cm);
        float p = (lane < cnt) ? __expf(e - mn) : 0.f;
        float cs = p;
#pragma unroll
        for (int off = 32; off; off >>= 1) cs += __shfl_xor(cs, off);
        float sc = __expf(m - mn);  // <= 1
        s = fmaf(s, sc, cs);
        acc *= sc;
        m = mn;
        // phase 2: weighted gather, lane = dim; batches of 4 independent loads
        int cnt4 = (cnt + 3) & ~3;
        for (int j = 0; j < cnt4; j += 4) {
            int s0 = __builtin_amdgcn_readlane(src, j);
            int s1 = __builtin_amdgcn_readlane(src, j + 1);
            int s2 = __builtin_amdgcn_readlane(src, j + 2);
            int s3 = __builtin_amdgcn_readlane(src, j + 3);
            float p0 = rdlane_f(p, j);
            float p1 = rdlane_f(p, j + 1);
            float p2 = rdlane_f(p, j + 2);
            float p3 = rdlane_f(p, j + 3);
            float h0 = hw[(size_t)s0 * 64 + lane];
            float h1 = hw[(size_t)s1 * 64 + lane];
            float h2 = hw[(size_t)s2 * 64 + lane];
            float h3 = hw[(size_t)s3 * 64 + lane];
            acc = fmaf(p0, h0, acc);
            acc = fmaf(p1, h1, acc);
            acc = fmaf(p2, h2, acc);
            acc = fmaf(p3, h3, acc);
        }
    }
    float o = acc / s + bv[lane];
    o = fminf(fmaxf(o, -1.f), 1.f);
    out[(size_t)i * 64 + lane] = o;
}

// ---------------- launch ----------------

extern "C" void kernel_launch(void* const* d_in, const int* in_sizes, int n_in, void* d_out, int out_size,
                              void* d_ws, size_t ws_size, hipStream_t stream) {
    const float* x = (const float*)d_in[0];
    const int* ei = (const int*)d_in[1];  // [2, NE] int32
    const float* W = (const float*)d_in[2];
    const float* a_s = (const float*)d_in[3];
    const float* a_d = (const float*)d_in[4];
    const float* b = (const float*)d_in[5];
    float* out = (float*)d_out;

    char* w = (char*)d_ws;
    auto alloc = [&](size_t bytes) -> char* {
        char* p = w;
        w += (bytes + 255) & ~(size_t)255;
        return p;
    };
    int* bcnt = (int*)alloc(256 * 4);
    int* bbase = (int*)alloc(257 * 4);
    int* bcur = (int*)alloc(256 * 4);
    int* offs = (int*)alloc((NN + 1) * 4);
    int* csr = (int*)alloc((size_t)NE * 4);
    // pairs (12.8 MB, CSR-build phase) aliases the als/ald/hwb region (layer phase)
    size_t layer_bytes = (size_t)(2 * NN + NN * DIM) * 4;
    size_t build_bytes = (size_t)NE * 8;
    char* region = alloc(layer_bytes > build_bytes ? layer_bytes : build_bytes);
    int2* pairs = (int2*)region;
    float* als = (float*)region;
    float* ald = als + NN;
    float* hwb = ald + NN;

    // CSR by dst (same inputs every call -> same work every call)
    hipMemsetAsync(bcnt, 0, 256 * 4, stream);
    k_bucket_hist<<<256, 256, 0, stream>>>(ei, bcnt);
    k_bucket_scan<<<1, 256, 0, stream>>>(bcnt, bbase, bcur, offs);
    k_partition<<<(NE + TILE - 1) / TILE, 256, 0, stream>>>(ei, bcur, pairs);
    k_node_csr<<<NBUCK, 256, 0, stream>>>(pairs, bbase, offs, csr);

    // 3 GAT layers; d_out doubles as the h ping buffer (h dead once hw computed)
    const float* hin = x;
    for (int l = 0; l < NL; l++) {
        k_transform<<<1600, 256, 0, stream>>>(hin, W + l * DIM * DIM, a_s + l * DIM, a_d + l * DIM, hwb, als, ald);
        k_aggregate<<<(NN + 3) / 4, 256, 0, stream>>>(hwb, als, ald, offs, csr, b + l * DIM, out);
        hin = out;
    }
}